// Round 11
// baseline (119.596 us; speedup 1.0000x reference)
//
#include <hip/hip_runtime.h>
#include <hip/hip_bf16.h>

// ConvEncoder: emb gather (padding_idx=0) + WIN=5 im2col + Linear(640->128) + exact GELU
// dtypes: x int32, emb/W/b float32, OUTPUT float32.
// Round 11: R8 occupancy (grid(512,2)=1024 blocks, 4/CU, 16 waves/CU) +
// R10 barrier-free K-loop (B per-lane from L2-hot fp32 W, inline cvt) +
// hand-unrolled staging (all token loads, then all emb loads: 2 serial
// latencies instead of 5 dependent chain iterations).

#define EMB   128
#define WIN   5
#define OUTC  128
#define SEQ   2048
#define KTOT  640
#define MTILE 64
#define NTILE 64

#define EMB_STRIDE 136   // elems; 272-B rows; 16-row-strided b128 reads 2-way aliased (free)
#define NCHUNK ((MTILE + WIN - 1) * 16)   // 1088 16-B chunks

typedef __bf16  bf16x8 __attribute__((ext_vector_type(8)));
typedef float   f32x4  __attribute__((ext_vector_type(4)));
typedef ushort  u16x8  __attribute__((ext_vector_type(8)));

__device__ inline ushort f2bf(float f) {
    __bf16 h = (__bf16)f;  // RNE
    return __builtin_bit_cast(ushort, h);
}

__device__ inline u16x8 cvt8v(float4 v0, float4 v1) {
    u16x8 o;
    o[0] = f2bf(v0.x); o[1] = f2bf(v0.y); o[2] = f2bf(v0.z); o[3] = f2bf(v0.w);
    o[4] = f2bf(v1.x); o[5] = f2bf(v1.y); o[6] = f2bf(v1.z); o[7] = f2bf(v1.w);
    return o;
}

__global__ __launch_bounds__(256, 4) void conv_encoder_kernel(
    const int* __restrict__ x,                 // (16, 2048)
    const float* __restrict__ emb,             // (50257, 128), row 0 zero
    const float* __restrict__ W,               // (128, 640)
    const float* __restrict__ bias,            // (128,)
    float* __restrict__ out)                   // (32768, 128)
{
    __shared__ ushort sEmb[(MTILE + WIN - 1) * EMB_STRIDE]; // 68 rows, 18.5 KB

    const int tid = threadIdx.x;
    const int m0  = blockIdx.x * MTILE;
    const int n0  = blockIdx.y * NTILE;
    const int bb  = m0 >> 11;
    const int s0  = m0 & (SEQ - 1);

    // ---- Staging, unrolled for ILP: 1088 chunks, thread t does t, t+256, ... ----
    {
        const int xbase = bb * SEQ;
        int tok[5];
        #pragma unroll
        for (int u = 0; u < 5; ++u) {            // phase 1: all token loads in flight
            const int idx = tid + u * 256;
            if (idx < NCHUNK) {
                const int s = s0 - 2 + (idx >> 4);
                tok[u] = (s >= 0 && s < SEQ) ? x[xbase + s] : 0;
            }
        }
        float4 v0[5], v1[5];
        #pragma unroll
        for (int u = 0; u < 5; ++u) {            // phase 2: all emb loads in flight
            const int idx = tid + u * 256;
            if (idx < NCHUNK) {
                const float* p = emb + (size_t)tok[u] * EMB + (idx & 15) * 8;
                v0[u] = *(const float4*)p;
                v1[u] = *(const float4*)(p + 4);
            }
        }
        #pragma unroll
        for (int u = 0; u < 5; ++u) {            // phase 3: cvt + LDS write
            const int idx = tid + u * 256;
            if (idx < NCHUNK)
                *(u16x8*)(&sEmb[(idx >> 4) * EMB_STRIDE + (idx & 15) * 8]) =
                    cvt8v(v0[u], v1[u]);
        }
    }
    __syncthreads();   // the ONLY barrier

    const int lane = tid & 63;
    const int wv   = tid >> 6;
    const int qr   = (wv >> 1) * 32;   // wave row base
    const int qc   = (wv & 1) * 32;    // wave col base
    const int lr   = lane & 15;
    const int lk8  = (lane >> 4) * 8;

    f32x4 acc[2][2];
    #pragma unroll
    for (int i = 0; i < 2; ++i)
        #pragma unroll
        for (int j = 0; j < 2; ++j)
            acc[i][j] = (f32x4){0.f, 0.f, 0.f, 0.f};

    // Per-lane fp32 W row bases: rows n0+qc+j*16+lr, k offset lk8
    const float* w0 = W + (size_t)(n0 + qc + lr) * KTOT + lk8;
    const float* w1 = w0 + 16 * KTOT;

    // ---- K loop: barrier-free; A from LDS, B from L2-hot fp32 W + inline cvt ----
    #pragma unroll
    for (int win = 0; win < WIN; ++win) {
        #pragma unroll
        for (int kc = 0; kc < 4; ++kc) {
            const int e  = kc * 32 + lk8;
            const int ko = win * EMB + kc * 32;
            bf16x8 bfr[2], afr[2];
            bfr[0] = __builtin_bit_cast(bf16x8,
                cvt8v(*(const float4*)(w0 + ko), *(const float4*)(w0 + ko + 4)));
            bfr[1] = __builtin_bit_cast(bf16x8,
                cvt8v(*(const float4*)(w1 + ko), *(const float4*)(w1 + ko + 4)));
            #pragma unroll
            for (int i = 0; i < 2; ++i)
                afr[i] = *(const bf16x8*)(&sEmb[(qr + i * 16 + lr + win) * EMB_STRIDE + e]);
            #pragma unroll
            for (int i = 0; i < 2; ++i)
                #pragma unroll
                for (int j = 0; j < 2; ++j)
                    acc[i][j] = __builtin_amdgcn_mfma_f32_16x16x32_bf16(afr[i], bfr[j], acc[i][j], 0, 0, 0);
        }
    }

    // ---- Epilogue: bias + exact GELU + fp32 store ----
    float bj[2];
    #pragma unroll
    for (int j = 0; j < 2; ++j)
        bj[j] = bias[n0 + qc + j * 16 + lr];

    const int rbase = (lane >> 4) * 4;
    #pragma unroll
    for (int i = 0; i < 2; ++i) {
        #pragma unroll
        for (int j = 0; j < 2; ++j) {
            const int col = n0 + qc + j * 16 + lr;
            #pragma unroll
            for (int r = 0; r < 4; ++r) {
                const int row = m0 + qr + i * 16 + rbase + r;
                const float y = acc[i][j][r] + bj[j];
                const float g = 0.5f * y * (1.0f + erff(y * 0.70710678118654752f));
                out[(size_t)row * OUTC + col] = g;
            }
        }
    }
}

extern "C" void kernel_launch(void* const* d_in, const int* in_sizes, int n_in,
                              void* d_out, int out_size, void* d_ws, size_t ws_size,
                              hipStream_t stream) {
    (void)in_sizes; (void)n_in; (void)d_ws; (void)ws_size; (void)out_size;
    const int* x        = (const int*)d_in[0];
    const float* emb    = (const float*)d_in[1];
    const float* Wm     = (const float*)d_in[2];
    const float* bias   = (const float*)d_in[3];
    float* out          = (float*)d_out;

    dim3 grid(32768 / MTILE, OUTC / NTILE);   // (512,2) = 1024 blocks -> 4/CU
    dim3 block(256);
    hipLaunchKernelGGL(conv_encoder_kernel, grid, block, 0, stream, x, emb, Wm, bias, out);
}

// Round 12
// 91.684 us; speedup vs baseline: 1.3044x; 1.3044x over previous
//
#include <hip/hip_runtime.h>
#include <hip/hip_bf16.h>

// ConvEncoder: emb gather (padding_idx=0) + WIN=5 im2col + Linear(640->128) + exact GELU
// dtypes: x int32, emb/W/b float32, OUTPUT float32.
// Round 12: R8 barrier structure, scaled up. 512-thread blocks (8 waves),
// MTILE=128 x NTILE=64, grid (256,2)=512 -> 2 blocks/CU x 8 waves = 16 waves/CU
// (best measured), per-CU VMEM bytes -31% vs R8 (emb staged once per 128 rows,
// W halves read by half as many blocks). B from LDS (R11 proved B-from-global
// costs ~2x). W prefetched to regs, issued AFTER the post-stage barrier.

#define EMB   128
#define WIN   5
#define OUTC  128
#define SEQ   2048
#define KTOT  640
#define MTILE 128
#define NTILE 64
#define BLK   512

#define EMB_STRIDE 136   // elems; 272-B rows; 16-row-strided b128 reads 2-way aliased (free)
#define SW_STRIDE  136
#define NCH_E ((MTILE + WIN - 1) * 16)   // 2112 16-B chunks of sEmb
#define NCH_W (NTILE * 16)               // 1024 16-B chunks of sW per window

typedef __bf16  bf16x8 __attribute__((ext_vector_type(8)));
typedef float   f32x4  __attribute__((ext_vector_type(4)));
typedef ushort  u16x8  __attribute__((ext_vector_type(8)));

__device__ inline ushort f2bf(float f) {
    __bf16 h = (__bf16)f;  // RNE
    return __builtin_bit_cast(ushort, h);
}

__device__ inline u16x8 cvt8v(float4 v0, float4 v1) {
    u16x8 o;
    o[0] = f2bf(v0.x); o[1] = f2bf(v0.y); o[2] = f2bf(v0.z); o[3] = f2bf(v0.w);
    o[4] = f2bf(v1.x); o[5] = f2bf(v1.y); o[6] = f2bf(v1.z); o[7] = f2bf(v1.w);
    return o;
}

__global__ __launch_bounds__(BLK, 4) void conv_encoder_kernel(
    const int* __restrict__ x,                 // (16, 2048)
    const float* __restrict__ emb,             // (50257, 128), row 0 zero
    const float* __restrict__ W,               // (128, 640)
    const float* __restrict__ bias,            // (128,)
    float* __restrict__ out)                   // (32768, 128)
{
    __shared__ ushort sEmb[(MTILE + WIN - 1) * EMB_STRIDE]; // 132 rows, 35.9 KB
    __shared__ ushort sW[NTILE * SW_STRIDE];                // 64 rows x 128-k window, 17.4 KB

    const int tid = threadIdx.x;
    const int m0  = blockIdx.x * MTILE;
    const int n0  = blockIdx.y * NTILE;    // pair blocks 256 apart -> same XCD (%8)
    const int bb  = m0 >> 11;
    const int s0  = m0 & (SEQ - 1);

    // ---- Window-0 W prefetch first (independent of gather chain): 2 chunks/thread ----
    float4 preA[2], preB[2];
    #pragma unroll
    for (int t = 0; t < 2; ++t) {
        const int idx = tid + t * BLK;
        const int r = idx >> 4, c = idx & 15;
        const float* p = W + (size_t)(n0 + r) * KTOT + c * 8;
        preA[t] = *(const float4*)p;
        preB[t] = *(const float4*)(p + 4);
    }

    // ---- Stage embeddings (132 rows x 128 elems), gather + cvt f32->bf16 ----
    {
        const int xbase = bb * SEQ;
        int toks[5];
        #pragma unroll
        for (int u = 0; u < 5; ++u) {           // all token loads issued up front
            const int idx = tid + u * BLK;
            if (idx < NCH_E) {
                const int s = s0 - 2 + (idx >> 4);
                toks[u] = (s >= 0 && s < SEQ) ? x[xbase + s] : 0;
            }
        }
        #pragma unroll
        for (int u = 0; u < 5; ++u) {           // load+cvt+store, pipelined by compiler
            const int idx = tid + u * BLK;
            if (idx < NCH_E) {
                const float* p = emb + (size_t)toks[u] * EMB + (idx & 15) * 8;
                *(u16x8*)(&sEmb[(idx >> 4) * EMB_STRIDE + (idx & 15) * 8]) =
                    cvt8v(*(const float4*)p, *(const float4*)(p + 4));
            }
        }
    }

    const int lane = tid & 63;
    const int wv   = tid >> 6;         // 0..7
    const int qr   = (wv >> 1) * 32;   // row quadrant (0,32,64,96)
    const int qc   = (wv & 1) * 32;    // col half (0,32)
    const int lr   = lane & 15;
    const int lk8  = (lane >> 4) * 8;

    f32x4 acc[2][2];
    #pragma unroll
    for (int i = 0; i < 2; ++i)
        #pragma unroll
        for (int j = 0; j < 2; ++j)
            acc[i][j] = (f32x4){0.f, 0.f, 0.f, 0.f};

    for (int win = 0; win < WIN; ++win) {
        __syncthreads();   // A: prior sW reads done (win 0: pairs with B for sEmb)
        #pragma unroll
        for (int t = 0; t < 2; ++t) {
            const int idx = tid + t * BLK;
            const int r = idx >> 4, c = idx & 15;
            *(u16x8*)(&sW[r * SW_STRIDE + c * 8]) = cvt8v(preA[t], preB[t]);
        }
        __syncthreads();   // B: sW (and, at win 0, sEmb) visible

        // Next window's W loads fly through the MFMA region; drained at next A.
        if (win + 1 < WIN) {
            #pragma unroll
            for (int t = 0; t < 2; ++t) {
                const int idx = tid + t * BLK;
                const int r = idx >> 4, c = idx & 15;
                const float* p = W + (size_t)(n0 + r) * KTOT + (win + 1) * EMB + c * 8;
                preA[t] = *(const float4*)p;
                preB[t] = *(const float4*)(p + 4);
            }
        }

        #pragma unroll
        for (int kc = 0; kc < 4; ++kc) {
            const int e = kc * 32 + lk8;
            bf16x8 afr[2], bfr[2];
            #pragma unroll
            for (int i = 0; i < 2; ++i)
                afr[i] = *(const bf16x8*)(&sEmb[(qr + i * 16 + lr + win) * EMB_STRIDE + e]);
            #pragma unroll
            for (int j = 0; j < 2; ++j)
                bfr[j] = *(const bf16x8*)(&sW[(qc + j * 16 + lr) * SW_STRIDE + e]);
            #pragma unroll
            for (int i = 0; i < 2; ++i)
                #pragma unroll
                for (int j = 0; j < 2; ++j)
                    acc[i][j] = __builtin_amdgcn_mfma_f32_16x16x32_bf16(afr[i], bfr[j], acc[i][j], 0, 0, 0);
        }
    }

    // ---- Epilogue: bias + exact GELU + fp32 store ----
    float bj[2];
    #pragma unroll
    for (int j = 0; j < 2; ++j)
        bj[j] = bias[n0 + qc + j * 16 + lr];

    const int rbase = (lane >> 4) * 4;
    #pragma unroll
    for (int i = 0; i < 2; ++i) {
        #pragma unroll
        for (int j = 0; j < 2; ++j) {
            const int col = n0 + qc + j * 16 + lr;
            #pragma unroll
            for (int r = 0; r < 4; ++r) {
                const int row = m0 + qr + i * 16 + rbase + r;
                const float y = acc[i][j][r] + bj[j];
                const float g = 0.5f * y * (1.0f + erff(y * 0.70710678118654752f));
                out[(size_t)row * OUTC + col] = g;
            }
        }
    }
}

extern "C" void kernel_launch(void* const* d_in, const int* in_sizes, int n_in,
                              void* d_out, int out_size, void* d_ws, size_t ws_size,
                              hipStream_t stream) {
    (void)in_sizes; (void)n_in; (void)d_ws; (void)ws_size; (void)out_size;
    const int* x        = (const int*)d_in[0];
    const float* emb    = (const float*)d_in[1];
    const float* Wm     = (const float*)d_in[2];
    const float* bias   = (const float*)d_in[3];
    float* out          = (float*)d_out;

    dim3 grid(32768 / MTILE, OUTC / NTILE);   // (256,2) = 512 blocks -> 2/CU, 16 waves/CU
    dim3 block(BLK);
    hipLaunchKernelGGL(conv_encoder_kernel, grid, block, 0, stream, x, emb, Wm, bias, out);
}